// Round 1
// baseline (63.781 us; speedup 1.0000x reference)
//
#include <hip/hip_runtime.h>

#define NEG_INF -1000000.0f

typedef __attribute__((ext_vector_type(8))) short short8;
typedef __attribute__((ext_vector_type(4))) float floatx4;

static __device__ __forceinline__ unsigned short f2bf(float f) {
    union { float f; unsigned int u; } v; v.f = f;
    unsigned int r = v.u + 0x7FFFu + ((v.u >> 16) & 1u);
    return (unsigned short)(r >> 16);
}

static __device__ __forceinline__ short8 pack8(const float4 a, const float4 b) {
    short8 r;
    r[0] = (short)f2bf(a.x); r[1] = (short)f2bf(a.y);
    r[2] = (short)f2bf(a.z); r[3] = (short)f2bf(a.w);
    r[4] = (short)f2bf(b.x); r[5] = (short)f2bf(b.y);
    r[6] = (short)f2bf(b.z); r[7] = (short)f2bf(b.w);
    return r;
}

// Block: 256 threads = 4 waves. Each block: one batch, 128 q-rows.
// Wave: 32 q-rows as 2 sub-tiles of 16. KV tile = 64 keys.
// mfma_f32_16x16x32_bf16 layouts (m89/m90-verified):
//   A: row = lane&15, k = (lane>>4)*8 + j   (8 consecutive k, b128 load)
//   B (from B^T rows): row(out col) = lane&15, k = (lane>>4)*8 + j
//   C/D: col = lane&15, row = (lane>>4)*4 + reg
__global__ __launch_bounds__(256, 2)
void attn_fwd(const float* __restrict__ Q, const float* __restrict__ K,
              const float* __restrict__ V, const int* __restrict__ vlen,
              float* __restrict__ out)
{
    // K tile row-major [64][64] padded to 72 (row stride 144B -> ~2-way banks)
    __shared__ __attribute__((aligned(16))) unsigned short K_lds[64 * 72];
    // V^T tile [dv=64][k=64] padded to 72, chunk-XOR swizzle: element (dv,k)
    // stored at dv*72 + ((k>>3)^(dv>>3))*8 + (k&7)  (conflict-free b16 scatter)
    __shared__ __attribute__((aligned(16))) unsigned short VT_lds[64 * 72];
    // per-wave P tile [16][64] padded to 72
    __shared__ __attribute__((aligned(16))) unsigned short P_lds[4 * 16 * 72];

    const int bid  = blockIdx.x;
    const int orig = (bid & 7) * 64 + (bid >> 3);   // XCD swizzle, bijective (512%8==0)
    const int b    = orig >> 3;                     // batch
    const int qb   = orig & 7;                      // q-block of 128 rows

    const int tid = threadIdx.x;
    const int l   = tid & 63;
    const int w   = tid >> 6;
    const int lr  = l & 15;
    const int lg  = l >> 4;

    const float* Qb = Q + (size_t)b * 1024 * 64;
    const float* Kb = K + (size_t)b * 1024 * 64;
    const float* Vb = V + (size_t)b * 1024 * 64;
    float*       Ob = out + (size_t)b * 1024 * 64;

    const int valid = vlen[b];
    const int kmax  = (valid == 0) ? 1024 : valid;  // valid==0: all masked -> uniform
    const int ntile = (kmax + 63) >> 6;

    // Q fragments (pre-scaled by 1/sqrt(64)=0.125, exact pow2)
    short8 qf[2][2];
#pragma unroll
    for (int s = 0; s < 2; ++s)
#pragma unroll
    for (int c = 0; c < 2; ++c) {
        const float* p = Qb + (size_t)(qb*128 + w*32 + s*16 + lr) * 64 + c*32 + lg*8;
        float4 a = *(const float4*)p, bb = *(const float4*)(p + 4);
        a.x *= 0.125f; a.y *= 0.125f; a.z *= 0.125f; a.w *= 0.125f;
        bb.x *= 0.125f; bb.y *= 0.125f; bb.z *= 0.125f; bb.w *= 0.125f;
        qf[s][c] = pack8(a, bb);
    }

    floatx4 o[2][4];
    float m[2][4], lsum[2][4];
#pragma unroll
    for (int s = 0; s < 2; ++s) {
#pragma unroll
        for (int n = 0; n < 4; ++n) o[s][n] = (floatx4){0.f, 0.f, 0.f, 0.f};
#pragma unroll
        for (int r = 0; r < 4; ++r) { m[s][r] = -INFINITY; lsum[s][r] = 0.f; }
    }

    for (int t = 0; t < ntile; ++t) {
        const int k0 = t * 64;
        __syncthreads();  // previous tile's frag reads done before overwrite
        // ---- stage K (row-major) and V (transposed+swizzled) as bf16 ----
#pragma unroll
        for (int i = 0; i < 2; ++i) {
            const int u  = tid + (i << 8);
            const int kr = u >> 3;          // 0..63 key row in tile
            const int c8 = (u & 7) << 3;    // 0..56 column group
            {
                const float* p = Kb + (size_t)(k0 + kr) * 64 + c8;
                float4 a = *(const float4*)p, bb = *(const float4*)(p + 4);
                *(short8*)&K_lds[kr*72 + c8] = pack8(a, bb);
            }
            {
                const float* p = Vb + (size_t)(k0 + kr) * 64 + c8;
                float4 a = *(const float4*)p, bb = *(const float4*)(p + 4);
                float vv[8] = {a.x, a.y, a.z, a.w, bb.x, bb.y, bb.z, bb.w};
#pragma unroll
                for (int j = 0; j < 8; ++j) {
                    const int dv = c8 + j;
                    const int cs = (kr >> 3) ^ (dv >> 3);
                    VT_lds[dv*72 + cs*8 + (kr & 7)] = f2bf(vv[j]);
                }
            }
        }
        __syncthreads();

        // ---- hoisted K / V^T fragments (shared by both q sub-tiles) ----
        short8 kf[2][4], vf[2][4];
#pragma unroll
        for (int c = 0; c < 2; ++c)
#pragma unroll
        for (int n = 0; n < 4; ++n) {
            kf[c][n] = *(const short8*)&K_lds[(n*16 + lr)*72 + c*32 + lg*8];
            const int dv = n*16 + lr;
            const int cs = (c*4 + lg) ^ (dv >> 3);
            vf[c][n] = *(const short8*)&VT_lds[dv*72 + cs*8];
        }

        const bool needMask = (k0 + 64) > valid;

#pragma unroll
        for (int s = 0; s < 2; ++s) {
            // QK^T: S[16q x 64k], lane holds q=lg*4+r, k=n*16+lr
            floatx4 sa[4];
#pragma unroll
            for (int n = 0; n < 4; ++n) {
                sa[n] = (floatx4){0.f, 0.f, 0.f, 0.f};
                sa[n] = __builtin_amdgcn_mfma_f32_16x16x32_bf16(qf[s][0], kf[0][n], sa[n], 0, 0, 0);
                sa[n] = __builtin_amdgcn_mfma_f32_16x16x32_bf16(qf[s][1], kf[1][n], sa[n], 0, 0, 0);
            }
            if (needMask) {
#pragma unroll
                for (int n = 0; n < 4; ++n) {
                    const bool msk = (k0 + n*16 + lr) >= valid;
#pragma unroll
                    for (int r = 0; r < 4; ++r) sa[n][r] = msk ? NEG_INF : sa[n][r];
                }
            }
            // row max over 4 n-tiles + 16 lanes (xor 8,4,2,1 stays in 16-group)
            float rmax[4];
#pragma unroll
            for (int r = 0; r < 4; ++r)
                rmax[r] = fmaxf(fmaxf(sa[0][r], sa[1][r]), fmaxf(sa[2][r], sa[3][r]));
#pragma unroll
            for (int off = 8; off >= 1; off >>= 1)
#pragma unroll
                for (int r = 0; r < 4; ++r)
                    rmax[r] = fmaxf(rmax[r], __shfl_xor(rmax[r], off));
            float nm[4], sc[4];
#pragma unroll
            for (int r = 0; r < 4; ++r) {
                nm[r]   = fmaxf(m[s][r], rmax[r]);
                sc[r]   = __expf(m[s][r] - nm[r]);   // first tile: exp(-inf)=0
                m[s][r] = nm[r];
            }
            float rs[4] = {0.f, 0.f, 0.f, 0.f};
            float pp[4][4];
#pragma unroll
            for (int n = 0; n < 4; ++n)
#pragma unroll
            for (int r = 0; r < 4; ++r) {
                pp[n][r] = __expf(sa[n][r] - nm[r]);  // masked: underflows to 0 (or 1 if all masked)
                rs[r] += pp[n][r];
            }
#pragma unroll
            for (int off = 8; off >= 1; off >>= 1)
#pragma unroll
                for (int r = 0; r < 4; ++r)
                    rs[r] += __shfl_xor(rs[r], off);
#pragma unroll
            for (int r = 0; r < 4; ++r) lsum[s][r] = lsum[s][r] * sc[r] + rs[r];
#pragma unroll
            for (int n = 0; n < 4; ++n)
#pragma unroll
            for (int r = 0; r < 4; ++r) o[s][n][r] *= sc[r];

            // P -> per-wave LDS tile, then read back as MFMA A-fragments
#pragma unroll
            for (int n = 0; n < 4; ++n)
#pragma unroll
            for (int r = 0; r < 4; ++r)
                P_lds[w*1152 + (lg*4 + r)*72 + n*16 + lr] = f2bf(pp[n][r]);

            short8 pa0 = *(const short8*)&P_lds[w*1152 + lr*72 + lg*8];
            short8 pa1 = *(const short8*)&P_lds[w*1152 + lr*72 + 32 + lg*8];
#pragma unroll
            for (int n = 0; n < 4; ++n) {
                o[s][n] = __builtin_amdgcn_mfma_f32_16x16x32_bf16(pa0, vf[0][n], o[s][n], 0, 0, 0);
                o[s][n] = __builtin_amdgcn_mfma_f32_16x16x32_bf16(pa1, vf[1][n], o[s][n], 0, 0, 0);
            }
        }
    }

    // ---- epilogue: normalize and store fp32 ----
#pragma unroll
    for (int s = 0; s < 2; ++s) {
        float inv[4];
#pragma unroll
        for (int r = 0; r < 4; ++r) inv[r] = 1.0f / lsum[s][r];
#pragma unroll
        for (int n = 0; n < 4; ++n)
#pragma unroll
        for (int r = 0; r < 4; ++r) {
            const int q = qb*128 + w*32 + s*16 + lg*4 + r;
            Ob[(size_t)q * 64 + n*16 + lr] = o[s][n][r] * inv[r];
        }
    }
}

extern "C" void kernel_launch(void* const* d_in, const int* in_sizes, int n_in,
                              void* d_out, int out_size, void* d_ws, size_t ws_size,
                              hipStream_t stream) {
    (void)in_sizes; (void)n_in; (void)d_ws; (void)ws_size; (void)out_size;
    const float* Q  = (const float*)d_in[0];
    const float* K  = (const float*)d_in[1];
    const float* V  = (const float*)d_in[2];
    const int*   vl = (const int*)d_in[3];
    float* O = (float*)d_out;
    attn_fwd<<<dim3(512), dim3(256), 0, stream>>>(Q, K, V, vl, O);
}

// Round 2
// 56.191 us; speedup vs baseline: 1.1351x; 1.1351x over previous
//
#include <hip/hip_runtime.h>

#define NEG_INF -1000000.0f

typedef __attribute__((ext_vector_type(8))) short short8;
typedef __attribute__((ext_vector_type(4))) float floatx4;

static __device__ __forceinline__ unsigned short f2bf(float f) {
    union { float f; unsigned int u; } v; v.f = f;
    unsigned int r = v.u + 0x7FFFu + ((v.u >> 16) & 1u);
    return (unsigned short)(r >> 16);
}

static __device__ __forceinline__ short8 pack8(const float4 a, const float4 b) {
    short8 r;
    r[0] = (short)f2bf(a.x); r[1] = (short)f2bf(a.y);
    r[2] = (short)f2bf(a.z); r[3] = (short)f2bf(a.w);
    r[4] = (short)f2bf(b.x); r[5] = (short)f2bf(b.y);
    r[6] = (short)f2bf(b.z); r[7] = (short)f2bf(b.w);
    return r;
}

// Block: 256 threads = 4 waves, 64 q-rows (wave owns one 16-row MFMA tile).
// Grid: 64 batches x 16 q-chunks = 1024 blocks, XCD-swizzled (bijective).
// KV tile = 64 keys, double-buffered LDS, regs-prefetch of tile t+1 issued
// before compute of tile t; ONE barrier per tile.
__global__ __launch_bounds__(256, 3)
void attn_fwd(const float* __restrict__ Q, const float* __restrict__ K,
              const float* __restrict__ V, const int* __restrict__ vlen,
              float* __restrict__ out)
{
    __shared__ __attribute__((aligned(16))) unsigned short K_lds[2][64 * 72];
    __shared__ __attribute__((aligned(16))) unsigned short VT_lds[2][64 * 72];
    __shared__ __attribute__((aligned(16))) unsigned short P_lds[4][16 * 72];

    const int bid  = blockIdx.x;
    const int orig = (bid & 7) * 128 + (bid >> 3);  // 1024%8==0 -> bijective
    const int b    = orig >> 4;                     // batch
    const int qc   = orig & 15;                     // q-chunk of 64 rows

    const int tid = threadIdx.x;
    const int l   = tid & 63;
    const int w   = tid >> 6;
    const int lr  = l & 15;
    const int lg  = l >> 4;

    const float* Qb = Q + (size_t)b * 65536;
    const float* Kb = K + (size_t)b * 65536;
    const float* Vb = V + (size_t)b * 65536;
    float*       Ob = out + (size_t)b * 65536;

    const int valid = vlen[b];
    const int kmax  = (valid == 0) ? 1024 : valid;  // all-masked -> uniform weights
    const int ntile = (kmax + 63) >> 6;

    // Q fragments, pre-scaled by 1/sqrt(64)
    short8 qf[2];
#pragma unroll
    for (int c = 0; c < 2; ++c) {
        const float* p = Qb + (size_t)(qc*64 + w*16 + lr) * 64 + c*32 + lg*8;
        float4 a = *(const float4*)p, bb = *(const float4*)(p + 4);
        a.x *= 0.125f; a.y *= 0.125f; a.z *= 0.125f; a.w *= 0.125f;
        bb.x *= 0.125f; bb.y *= 0.125f; bb.z *= 0.125f; bb.w *= 0.125f;
        qf[c] = pack8(a, bb);
    }

    floatx4 o[4];
    float m[4], lsum[4];
#pragma unroll
    for (int n = 0; n < 4; ++n) o[n] = (floatx4){0.f, 0.f, 0.f, 0.f};
#pragma unroll
    for (int r = 0; r < 4; ++r) { m[r] = -INFINITY; lsum[r] = 0.f; }

    const int kr = tid >> 3;         // 0..31 (i adds 32)
    const int c8 = (tid & 7) << 3;   // 0..56

    float4 kra[2][2], vra[2][2];

#define LOAD_TILE(T) do {                                                     \
    const int _k0 = (T) * 64;                                                 \
    _Pragma("unroll")                                                         \
    for (int i = 0; i < 2; ++i) {                                             \
        const float* pk = Kb + (size_t)(_k0 + kr + i*32) * 64 + c8;           \
        kra[i][0] = *(const float4*)pk; kra[i][1] = *(const float4*)(pk + 4); \
        const float* pv = Vb + (size_t)(_k0 + kr + i*32) * 64 + c8;           \
        vra[i][0] = *(const float4*)pv; vra[i][1] = *(const float4*)(pv + 4); \
    } } while (0)

#define WRITE_TILE(B) do {                                                    \
    _Pragma("unroll")                                                         \
    for (int i = 0; i < 2; ++i) {                                             \
        const int krr = kr + i*32;                                            \
        *(short8*)&K_lds[B][krr*72 + c8] = pack8(kra[i][0], kra[i][1]);       \
        float vv[8] = {vra[i][0].x, vra[i][0].y, vra[i][0].z, vra[i][0].w,    \
                       vra[i][1].x, vra[i][1].y, vra[i][1].z, vra[i][1].w};   \
        _Pragma("unroll")                                                     \
        for (int j = 0; j < 8; ++j) {                                         \
            const int dv = c8 + j;                                            \
            const int cs = (krr >> 3) ^ (dv >> 3);                            \
            VT_lds[B][dv*72 + cs*8 + (krr & 7)] = f2bf(vv[j]);                \
        }                                                                     \
    } } while (0)

    LOAD_TILE(0);
    WRITE_TILE(0);
    __syncthreads();

    for (int t = 0; t < ntile; ++t) {
        const int cur = t & 1;
        const int k0  = t * 64;

        if (t + 1 < ntile) LOAD_TILE(t + 1);   // in flight during compute

        // ---- QK^T: S[16q x 64k]; lane holds q=lg*4+r, k=n*16+lr ----
        floatx4 sa[4];
#pragma unroll
        for (int n = 0; n < 4; ++n) {
            const short8 kf0 = *(const short8*)&K_lds[cur][(n*16 + lr)*72 + lg*8];
            const short8 kf1 = *(const short8*)&K_lds[cur][(n*16 + lr)*72 + 32 + lg*8];
            sa[n] = (floatx4){0.f, 0.f, 0.f, 0.f};
            sa[n] = __builtin_amdgcn_mfma_f32_16x16x32_bf16(qf[0], kf0, sa[n], 0, 0, 0);
            sa[n] = __builtin_amdgcn_mfma_f32_16x16x32_bf16(qf[1], kf1, sa[n], 0, 0, 0);
        }

        if ((k0 + 64) > valid) {
#pragma unroll
            for (int n = 0; n < 4; ++n) {
                const bool msk = (k0 + n*16 + lr) >= valid;
#pragma unroll
                for (int r = 0; r < 4; ++r) sa[n][r] = msk ? NEG_INF : sa[n][r];
            }
        }

        // ---- online softmax (16-lane group reductions) ----
        float rmax[4];
#pragma unroll
        for (int r = 0; r < 4; ++r)
            rmax[r] = fmaxf(fmaxf(sa[0][r], sa[1][r]), fmaxf(sa[2][r], sa[3][r]));
#pragma unroll
        for (int off = 8; off >= 1; off >>= 1)
#pragma unroll
            for (int r = 0; r < 4; ++r)
                rmax[r] = fmaxf(rmax[r], __shfl_xor(rmax[r], off));
        float nm[4], sc[4];
#pragma unroll
        for (int r = 0; r < 4; ++r) {
            nm[r] = fmaxf(m[r], rmax[r]);
            sc[r] = __expf(m[r] - nm[r]);     // first tile: exp(-inf)=0
            m[r]  = nm[r];
        }
        float rs[4] = {0.f, 0.f, 0.f, 0.f};
        float pp[4][4];
#pragma unroll
        for (int n = 0; n < 4; ++n)
#pragma unroll
        for (int r = 0; r < 4; ++r) {
            pp[n][r] = __expf(sa[n][r] - nm[r]);
            rs[r] += pp[n][r];
        }
#pragma unroll
        for (int off = 8; off >= 1; off >>= 1)
#pragma unroll
            for (int r = 0; r < 4; ++r)
                rs[r] += __shfl_xor(rs[r], off);
#pragma unroll
        for (int r = 0; r < 4; ++r) lsum[r] = lsum[r] * sc[r] + rs[r];
#pragma unroll
        for (int n = 0; n < 4; ++n)
#pragma unroll
        for (int r = 0; r < 4; ++r) o[n][r] *= sc[r];

        // ---- P -> per-wave LDS, read back as A-fragments ----
#pragma unroll
        for (int n = 0; n < 4; ++n)
#pragma unroll
        for (int r = 0; r < 4; ++r)
            P_lds[w][(lg*4 + r)*72 + n*16 + lr] = f2bf(pp[n][r]);

        const short8 pa0 = *(const short8*)&P_lds[w][lr*72 + lg*8];
        const short8 pa1 = *(const short8*)&P_lds[w][lr*72 + 32 + lg*8];

        // ---- PV ----
#pragma unroll
        for (int n = 0; n < 4; ++n) {
            const int dv = n*16 + lr;
            const short8 vf0 = *(const short8*)&VT_lds[cur][dv*72 + ((lg    ) ^ (dv >> 3))*8];
            const short8 vf1 = *(const short8*)&VT_lds[cur][dv*72 + ((4 + lg) ^ (dv >> 3))*8];
            o[n] = __builtin_amdgcn_mfma_f32_16x16x32_bf16(pa0, vf0, o[n], 0, 0, 0);
            o[n] = __builtin_amdgcn_mfma_f32_16x16x32_bf16(pa1, vf1, o[n], 0, 0, 0);
        }

        if (t + 1 < ntile) WRITE_TILE(cur ^ 1);  // vmcnt wait lands here, after compute
        __syncthreads();                         // single barrier per tile
    }

    // ---- epilogue ----
    float inv[4];
#pragma unroll
    for (int r = 0; r < 4; ++r) inv[r] = 1.0f / lsum[r];
#pragma unroll
    for (int n = 0; n < 4; ++n)
#pragma unroll
    for (int r = 0; r < 4; ++r) {
        const int q = qc*64 + w*16 + lg*4 + r;
        Ob[(size_t)q * 64 + n*16 + lr] = o[n][r] * inv[r];
    }
#undef LOAD_TILE
#undef WRITE_TILE
}

extern "C" void kernel_launch(void* const* d_in, const int* in_sizes, int n_in,
                              void* d_out, int out_size, void* d_ws, size_t ws_size,
                              hipStream_t stream) {
    (void)in_sizes; (void)n_in; (void)d_ws; (void)ws_size; (void)out_size;
    const float* Q  = (const float*)d_in[0];
    const float* K  = (const float*)d_in[1];
    const float* V  = (const float*)d_in[2];
    const int*   vl = (const int*)d_in[3];
    float* O = (float*)d_out;
    attn_fwd<<<dim3(1024), dim3(256), 0, stream>>>(Q, K, V, vl, O);
}